// Round 1
// 173.779 us; speedup vs baseline: 1.0359x; 1.0359x over previous
//
#include <hip/hip_runtime.h>
#include <stdint.h>

#define M_DIM 2048
#define N_DIM 4096
#define K_DIM 4096
#define NGROUP 32
#define GSIZE 128

#define RQ_UP   (127.0f / 15.0f)   // weight requant gain
#define RQ_DOWN (15.0f / 127.0f)

// ---------------------------------------------------------------------------
// GEMM geometry: 256x128 tile, 8 waves (512 thr) as 4(M) x 2(N), each wave a
// 64x64 sub-tile = 4x4 frags of 16x16x64 i8 MFMA.
// K pipelined in 64-byte slices, DEPTH=4 LDS slots, prefetch distance 3.
// Counted vmcnt (never 0 in steady state) + raw s_barrier + setprio  [T3/T4/T5].
// LDS swizzle: 16B chunk c of row r stored at slot c ^ ((r>>1)&3) within the
// 64B row -> ds_read_b128 by 16-lane groups lands 2-way max (free, m136).
// ---------------------------------------------------------------------------
#define BM 256
#define BN 128
#define KSLICE 64
#define NSLICE (K_DIM / KSLICE)    // 64
#define ASLOT (BM * KSLICE)        // 16 KiB
#define BSLOT (BN * KSLICE)        //  8 KiB

typedef __attribute__((ext_vector_type(4))) int int32x4_t;

static __device__ __forceinline__ void gl2lds16(const void* g, void* l) {
    auto gp = (const __attribute__((address_space(1))) unsigned int*)(uintptr_t)g;
    auto lp = (__attribute__((address_space(3))) unsigned int*)(uintptr_t)l;
    __builtin_amdgcn_global_load_lds(gp, lp, 16, 0, 0);
}

#define WAITVM_(N) asm volatile("s_waitcnt vmcnt(" #N ")" ::: "memory")
#define WAITVM(N) WAITVM_(N)
#define BARRIER() asm volatile("s_barrier" ::: "memory")

// ---------------------------------------------------------------------------
// Fused prep (absorbs old sn_kernel):
//   [0, 2048): per-token activation quant -> A8 = (q-128) int8, xscale, czp
//   [2048, ..): weight requant. rsn[n] = RQ_UP / max_g ws[n][g] is computed
//   in-cluster: 16 lanes of a group-cluster each read 2 of the 32 scales,
//   4-step shfl_xor max (exact: max is associative).
// ---------------------------------------------------------------------------
#define QUANT_BLOCKS M_DIM
#define DEQ_BLOCKS ((N_DIM * K_DIM) / 8 / 256)       // 8 codes / thread

__global__ __launch_bounds__(256) void prep_kernel(
        const float* __restrict__ x,
        const int* __restrict__ qw,          // [N][K] codes 0..15 as int32
        const float* __restrict__ wsc,       // [N][32]
        const int* __restrict__ wzp,         // [N][32]
        char* __restrict__ A8,               // [M][K] int8 (q-128)
        char* __restrict__ Bt8,              // [N][K] int8 requantized
        float* __restrict__ xscale,          // [M]
        float* __restrict__ xzpc,            // [M]  = 128 - zp
        int* __restrict__ Sw)                // [N][32] group sums of Bt8
{
    const int t = threadIdx.x;
    if (blockIdx.x < QUANT_BLOCKS) {
        const int s = blockIdx.x;
        const float* xrow = x + (size_t)s * K_DIM;

        float xv[16];
        float vmin = 1e38f, vmax = -1e38f;
#pragma unroll
        for (int p = 0; p < 4; ++p) {
            float4 v = *((const float4*)(xrow + p * 1024) + t);
            xv[p*4+0] = v.x; xv[p*4+1] = v.y; xv[p*4+2] = v.z; xv[p*4+3] = v.w;
            vmin = fminf(vmin, fminf(fminf(v.x, v.y), fminf(v.z, v.w)));
            vmax = fmaxf(vmax, fmaxf(fmaxf(v.x, v.y), fmaxf(v.z, v.w)));
        }
#pragma unroll
        for (int off = 32; off > 0; off >>= 1) {
            vmin = fminf(vmin, __shfl_xor(vmin, off));
            vmax = fmaxf(vmax, __shfl_xor(vmax, off));
        }
        __shared__ float smin[4], smax[4];
        const int wave = t >> 6;
        if ((t & 63) == 0) { smin[wave] = vmin; smax[wave] = vmax; }
        __syncthreads();
        vmin = fminf(fminf(smin[0], smin[1]), fminf(smin[2], smin[3]));
        vmax = fmaxf(fmaxf(smax[0], smax[1]), fmaxf(smax[2], smax[3]));

        float sc = (vmax - vmin) / 255.0f;
        sc = fmaxf(sc, 1e-5f);
        float zp = rintf(-vmin / sc);
        zp = fminf(fmaxf(zp, 0.0f), 255.0f);

#pragma unroll
        for (int p = 0; p < 4; ++p) {
            int b[4];
#pragma unroll
            for (int e = 0; e < 4; ++e) {
                float q = fminf(fmaxf(rintf(xv[p*4+e] / sc) + zp, 0.0f), 255.0f);
                b[e] = (int)q - 128;
            }
            unsigned pack = (b[0] & 0xff) | ((b[1] & 0xff) << 8) |
                            ((b[2] & 0xff) << 16) | ((b[3] & 0xff) << 24);
            *(unsigned*)(A8 + (size_t)s * K_DIM + p * 1024 + t * 4) = pack;
        }
        if (t == 0) { xscale[s] = sc; xzpc[s] = 128.0f - zp; }
    } else {
        // ---- weight requant: 8 codes/thread; 16-lane cluster = 1 group ----
        const size_t base = ((size_t)(blockIdx.x - QUANT_BLOCKS) * 256 + t) * 8;
        const int n = (int)(base >> 12);          // /4096
        const int g = (int)((base >> 7) & 31);
        const int zp = wzp[n * NGROUP + g];

        // inline rsn: row max of the 32 scales across the 16-lane cluster
        const int cl = t & 15;
        float2 wp = *(const float2*)(wsc + (size_t)n * NGROUP + cl * 2);
        float smx = fmaxf(wp.x, wp.y);
#pragma unroll
        for (int off = 1; off < 16; off <<= 1)
            smx = fmaxf(smx, __shfl_xor(smx, off));
        const float factor = wsc[n * NGROUP + g] * (RQ_UP / smx);   // <= 127/15

        int4 c0 = *(const int4*)(qw + base);
        int4 c1 = *(const int4*)(qw + base + 4);
        int w[8];
        w[0] = (int)rintf((float)(c0.x - zp) * factor);
        w[1] = (int)rintf((float)(c0.y - zp) * factor);
        w[2] = (int)rintf((float)(c0.z - zp) * factor);
        w[3] = (int)rintf((float)(c0.w - zp) * factor);
        w[4] = (int)rintf((float)(c1.x - zp) * factor);
        w[5] = (int)rintf((float)(c1.y - zp) * factor);
        w[6] = (int)rintf((float)(c1.z - zp) * factor);
        w[7] = (int)rintf((float)(c1.w - zp) * factor);
        uint2 pk;
        pk.x = (w[0] & 0xff) | ((w[1] & 0xff) << 8) | ((w[2] & 0xff) << 16) | ((w[3] & 0xff) << 24);
        pk.y = (w[4] & 0xff) | ((w[5] & 0xff) << 8) | ((w[6] & 0xff) << 16) | ((w[7] & 0xff) << 24);
        *(uint2*)(Bt8 + base) = pk;

        int s8 = w[0] + w[1] + w[2] + w[3] + w[4] + w[5] + w[6] + w[7];
#pragma unroll
        for (int off = 1; off < 16; off <<= 1) s8 += __shfl_xor(s8, off);
        if ((t & 15) == 0)
            Sw[n * NGROUP + g] = s8;     // coalesced, no atomic
    }
}

// ---------------------------------------------------------------------------
// Pipelined i8 GEMM. Epilogue (absorbs old ws_kernel):
//   out[m][n] = xscale[m]*(fws[n]*iacc + czp[m]*WSf[n]) + bias[n]
//   fws[n] = RQ_DOWN * max_g ws[n][g];  WSf[n] = fws[n] * sum_g Sw[n][g]
// ---------------------------------------------------------------------------
__global__ __launch_bounds__(512, 2) void gemm_kernel(
        const char* __restrict__ A8,     // [M][K] int8
        const char* __restrict__ Bt8,    // [N][K] int8
        const float* __restrict__ xscale,
        const float* __restrict__ xzpc,
        const float* __restrict__ wsc,   // [N][32]
        const int* __restrict__ Sw,      // [N][32]
        const float* __restrict__ bias,  // [N]
        float* __restrict__ out)         // [M][N] f32
{
    __shared__ __align__(16) char As[4][ASLOT];   // 64 KiB
    __shared__ __align__(16) char Bs[4][BSLOT];   // 32 KiB
    __shared__ float fws_s[BN], wsf_s[BN];

    const int tid  = threadIdx.x;
    const int bn   = blockIdx.x;
    const int bm   = blockIdx.y;
    const int wave = tid >> 6;
    const int lane = tid & 63;
    const int wr   = wave >> 1;          // 0..3  -> 64-row band
    const int wcl  = wave & 1;           // 0..1  -> 64-col band
    const int lrow  = lane & 15;
    const int lquad = lane >> 4;         // 0..3 -> 16B k-chunk

    // --- per-column epilogue constants (old sn/ws kernels), before pipeline ---
    if (tid < BN) {
        const int n = bn * BN + tid;
        const int4* s4 = (const int4*)(Sw + (size_t)n * NGROUP);
        int acc = 0;
#pragma unroll
        for (int p = 0; p < 8; ++p) { int4 v = s4[p]; acc += v.x + v.y + v.z + v.w; }
        const float4* w4 = (const float4*)(wsc + (size_t)n * NGROUP);
        float s = 0.f;
#pragma unroll
        for (int p = 0; p < 8; ++p) {
            float4 w = w4[p];
            s = fmaxf(s, fmaxf(fmaxf(w.x, w.y), fmaxf(w.z, w.w)));
        }
        const float fw = s * RQ_DOWN;
        fws_s[tid] = fw;
        wsf_s[tid] = fw * (float)acc;
    }
    // drain prologue vmem (clean vmcnt baseline for counted waits) + publish LDS
    asm volatile("s_waitcnt vmcnt(0) lgkmcnt(0)" ::: "memory");
    BARRIER();

    // --- staging addresses: gl2lds dst = uniform base + lane*16 (m104).
    // lane -> (row_local = lane>>2, eff_chunk = lane&3); source chunk is
    // eff_chunk ^ ((row>>1)&3) = (lane&3) ^ ((lane>>3)&3)  (rbase % 16 == 0).
    const char* Ab = A8  + (size_t)(bm * BM) * K_DIM;
    const char* Bb = Bt8 + (size_t)(bn * BN) * K_DIM;
    const int lsub = lane >> 2;
    const int csrc = (lane & 3) ^ ((lane >> 3) & 3);
    const char* gA0 = Ab + (size_t)((wave      ) * 16 + lsub) * K_DIM + csrc * 16;
    const char* gA1 = Ab + (size_t)((wave + 8  ) * 16 + lsub) * K_DIM + csrc * 16;
    const char* gB0 = Bb + (size_t)((wave      ) * 16 + lsub) * K_DIM + csrc * 16;
    const int lA0 = wave * 1024;
    const int lA1 = 8192 + wave * 1024;
    const int lB0 = wave * 1024;

    // --- ds_read offsets (slot-relative), swizzle matches staging involution ---
    const int xq = (lquad ^ ((lrow >> 1) & 3)) * 16;
    int aoff[4], boff[4];
#pragma unroll
    for (int i = 0; i < 4; ++i)
        aoff[i] = (wr * 64 + i * 16 + lrow) * KSLICE + xq;
#pragma unroll
    for (int j = 0; j < 4; ++j)
        boff[j] = (wcl * 64 + j * 16 + lrow) * KSLICE + xq;

    int32x4_t iacc[4][4];
    const int32x4_t zi = {0, 0, 0, 0};
#pragma unroll
    for (int i = 0; i < 4; ++i)
#pragma unroll
        for (int j = 0; j < 4; ++j) iacc[i][j] = zi;

#define STAGE(t) {                                                   \
        const int sl_ = (t) & 3;                                     \
        const size_t k0_ = (size_t)(t) * KSLICE;                     \
        gl2lds16(gA0 + k0_, &As[sl_][0] + lA0);                      \
        gl2lds16(gA1 + k0_, &As[sl_][0] + lA1);                      \
        gl2lds16(gB0 + k0_, &Bs[sl_][0] + lB0);                      \
    }

    // Per slice: issue stage(s+3) [slot (s-1)&3, freed by previous trailing
    // barrier]; WAITVM(9) leaves stages s+1..s+3 (9 loads) in flight while
    // guaranteeing stage(s) landed; barrier publishes slot; 8 ds_read_b128 +
    // 16 MFMA under setprio; trailing barrier frees slot s&3 for stage(s+4).
#define SLICE(s, VMN) {                                              \
        if ((s) + 3 < NSLICE) STAGE((s) + 3);                        \
        WAITVM(VMN);                                                 \
        BARRIER();                                                   \
        const char* Ap_ = &As[(s) & 3][0];                           \
        const char* Bp_ = &Bs[(s) & 3][0];                           \
        int32x4_t af_[4], bf_[4];                                    \
        _Pragma("unroll")                                            \
        for (int i_ = 0; i_ < 4; ++i_)                               \
            af_[i_] = *(const int32x4_t*)(Ap_ + aoff[i_]);           \
        _Pragma("unroll")                                            \
        for (int j_ = 0; j_ < 4; ++j_)                               \
            bf_[j_] = *(const int32x4_t*)(Bp_ + boff[j_]);           \
        __builtin_amdgcn_s_setprio(1);                               \
        _Pragma("unroll")                                            \
        for (int i_ = 0; i_ < 4; ++i_)                               \
            _Pragma("unroll")                                        \
            for (int j_ = 0; j_ < 4; ++j_)                           \
                iacc[i_][j_] = __builtin_amdgcn_mfma_i32_16x16x64_i8(\
                    af_[i_], bf_[j_], iacc[i_][j_], 0, 0, 0);        \
        __builtin_amdgcn_s_setprio(0);                               \
        BARRIER();                                                   \
    }

    STAGE(0); STAGE(1); STAGE(2);          // fill: 9 loads in flight

    for (int s = 0; s < NSLICE - 3; ++s)   // steady state: vmcnt(9)
        SLICE(s, 9);
    SLICE(NSLICE - 3, 6);                  // drain: 6, 3, 0
    SLICE(NSLICE - 2, 3);
    SLICE(NSLICE - 1, 0);

    // --- epilogue: C/D layout col=lane&15, row=lquad*4+reg ---
    float fn[4], wf[4], bb[4];
    int ncol[4];
#pragma unroll
    for (int j = 0; j < 4; ++j) {
        const int ncl = wcl * 64 + j * 16 + lrow;
        ncol[j] = bn * BN + ncl;
        fn[j] = fws_s[ncl];
        wf[j] = wsf_s[ncl];
        bb[j] = bias[ncol[j]];
    }
    const int m0 = bm * BM + wr * 64;
#pragma unroll
    for (int i = 0; i < 4; ++i) {
#pragma unroll
        for (int r = 0; r < 4; ++r) {
            const int m = m0 + i * 16 + lquad * 4 + r;
            const float xs  = xscale[m];
            const float czp = xzpc[m];
            float* orow = out + (size_t)m * N_DIM;
#pragma unroll
            for (int j = 0; j < 4; ++j)
                orow[ncol[j]] = xs * (fn[j] * (float)iacc[i][j][r] + czp * wf[j]) + bb[j];
        }
    }
#undef SLICE
#undef STAGE
}

extern "C" void kernel_launch(void* const* d_in, const int* in_sizes, int n_in,
                              void* d_out, int out_size, void* d_ws, size_t ws_size,
                              hipStream_t stream) {
    const float* x     = (const float*)d_in[0];
    const int*   qw    = (const int*)d_in[1];
    const float* wsc   = (const float*)d_in[2];
    const int*   wzp   = (const int*)d_in[3];
    const float* bias  = (const float*)d_in[4];
    float* out = (float*)d_out;

    // workspace layout
    char* A8  = (char*)d_ws;                                   //  8 MiB
    char* Bt8 = A8 + (size_t)M_DIM * K_DIM;                    // 16 MiB
    float* xscale = (float*)(Bt8 + (size_t)N_DIM * K_DIM);     //  8 KiB
    float* xzpc   = xscale + M_DIM;                            //  8 KiB
    int*   Sw     = (int*)(xzpc + M_DIM);                      // 512 KiB

    prep_kernel<<<QUANT_BLOCKS + DEQ_BLOCKS, 256, 0, stream>>>(
        x, qw, wsc, wzp, A8, Bt8, xscale, xzpc, Sw);
    dim3 grid(N_DIM / BN, M_DIM / BM);
    gemm_kernel<<<grid, 512, 0, stream>>>(A8, Bt8, xscale, xzpc, wsc, Sw, bias, out);
}

// Round 2
// 169.569 us; speedup vs baseline: 1.0616x; 1.0248x over previous
//
#include <hip/hip_runtime.h>
#include <stdint.h>

#define M_DIM 2048
#define N_DIM 4096
#define K_DIM 4096
#define NGROUP 32
#define GSIZE 128

#define RQ_UP   (127.0f / 15.0f)   // weight requant gain
#define RQ_DOWN (15.0f / 127.0f)

// ---------------------------------------------------------------------------
// GEMM geometry (unchanged from R1, verified correct, 0 bank conflicts):
// 256x128 tile, 8 waves (512 thr) as 4(M) x 2(N), each wave 64x64 = 4x4 frags
// of 16x16x64 i8 MFMA. K pipelined in 64-byte slices, 4 LDS slots, prefetch
// distance 3, counted vmcnt.
// R2 change: fragment REGISTER double-buffering — body(s) issues ds_read for
// slice s+1, waits lgkmcnt(8) (slice s's reads only), MFMAs slice s while
// s+1's reads + stage s+3's DMA are in flight. Even/odd reg sets (rule #20).
// ---------------------------------------------------------------------------
#define BM 256
#define BN 128
#define KSLICE 64
#define NSLICE (K_DIM / KSLICE)    // 64
#define ASLOT (BM * KSLICE)        // 16 KiB
#define BSLOT (BN * KSLICE)        //  8 KiB

typedef __attribute__((ext_vector_type(4))) int int32x4_t;

static __device__ __forceinline__ void gl2lds16(const void* g, void* l) {
    auto gp = (const __attribute__((address_space(1))) unsigned int*)(uintptr_t)g;
    auto lp = (__attribute__((address_space(3))) unsigned int*)(uintptr_t)l;
    __builtin_amdgcn_global_load_lds(gp, lp, 16, 0, 0);
}

#define WAITVM_(N) asm volatile("s_waitcnt vmcnt(" #N ")" ::: "memory")
#define WAITVM(N) WAITVM_(N)
#define WAITLGKM_(N) asm volatile("s_waitcnt lgkmcnt(" #N ")" ::: "memory")
#define WAITLGKM(N) WAITLGKM_(N)
#define BARRIER() asm volatile("s_barrier" ::: "memory")

// ---------------------------------------------------------------------------
// Fused prep:
//   [0, 2048): per-token activation quant -> A8 = (q-128) int8, xscale, czp
//   [2048, ..): weight requant; rsn computed in-cluster via shfl_xor max.
// ---------------------------------------------------------------------------
#define QUANT_BLOCKS M_DIM
#define DEQ_BLOCKS ((N_DIM * K_DIM) / 8 / 256)       // 8 codes / thread

__global__ __launch_bounds__(256) void prep_kernel(
        const float* __restrict__ x,
        const int* __restrict__ qw,          // [N][K] codes 0..15 as int32
        const float* __restrict__ wsc,       // [N][32]
        const int* __restrict__ wzp,         // [N][32]
        char* __restrict__ A8,               // [M][K] int8 (q-128)
        char* __restrict__ Bt8,              // [N][K] int8 requantized
        float* __restrict__ xscale,          // [M]
        float* __restrict__ xzpc,            // [M]  = 128 - zp
        int* __restrict__ Sw)                // [N][32] group sums of Bt8
{
    const int t = threadIdx.x;
    if (blockIdx.x < QUANT_BLOCKS) {
        const int s = blockIdx.x;
        const float* xrow = x + (size_t)s * K_DIM;

        float xv[16];
        float vmin = 1e38f, vmax = -1e38f;
#pragma unroll
        for (int p = 0; p < 4; ++p) {
            float4 v = *((const float4*)(xrow + p * 1024) + t);
            xv[p*4+0] = v.x; xv[p*4+1] = v.y; xv[p*4+2] = v.z; xv[p*4+3] = v.w;
            vmin = fminf(vmin, fminf(fminf(v.x, v.y), fminf(v.z, v.w)));
            vmax = fmaxf(vmax, fmaxf(fmaxf(v.x, v.y), fmaxf(v.z, v.w)));
        }
#pragma unroll
        for (int off = 32; off > 0; off >>= 1) {
            vmin = fminf(vmin, __shfl_xor(vmin, off));
            vmax = fmaxf(vmax, __shfl_xor(vmax, off));
        }
        __shared__ float smin[4], smax[4];
        const int wave = t >> 6;
        if ((t & 63) == 0) { smin[wave] = vmin; smax[wave] = vmax; }
        __syncthreads();
        vmin = fminf(fminf(smin[0], smin[1]), fminf(smin[2], smin[3]));
        vmax = fmaxf(fmaxf(smax[0], smax[1]), fmaxf(smax[2], smax[3]));

        float sc = (vmax - vmin) / 255.0f;
        sc = fmaxf(sc, 1e-5f);
        float zp = rintf(-vmin / sc);
        zp = fminf(fmaxf(zp, 0.0f), 255.0f);

#pragma unroll
        for (int p = 0; p < 4; ++p) {
            int b[4];
#pragma unroll
            for (int e = 0; e < 4; ++e) {
                float q = fminf(fmaxf(rintf(xv[p*4+e] / sc) + zp, 0.0f), 255.0f);
                b[e] = (int)q - 128;
            }
            unsigned pack = (b[0] & 0xff) | ((b[1] & 0xff) << 8) |
                            ((b[2] & 0xff) << 16) | ((b[3] & 0xff) << 24);
            *(unsigned*)(A8 + (size_t)s * K_DIM + p * 1024 + t * 4) = pack;
        }
        if (t == 0) { xscale[s] = sc; xzpc[s] = 128.0f - zp; }
    } else {
        // ---- weight requant: 8 codes/thread; 16-lane cluster = 1 group ----
        const size_t base = ((size_t)(blockIdx.x - QUANT_BLOCKS) * 256 + t) * 8;
        const int n = (int)(base >> 12);          // /4096
        const int g = (int)((base >> 7) & 31);
        const int zp = wzp[n * NGROUP + g];

        // inline rsn: row max of the 32 scales across the 16-lane cluster
        const int cl = t & 15;
        float2 wp = *(const float2*)(wsc + (size_t)n * NGROUP + cl * 2);
        float smx = fmaxf(wp.x, wp.y);
#pragma unroll
        for (int off = 1; off < 16; off <<= 1)
            smx = fmaxf(smx, __shfl_xor(smx, off));
        const float factor = wsc[n * NGROUP + g] * (RQ_UP / smx);   // <= 127/15

        int4 c0 = *(const int4*)(qw + base);
        int4 c1 = *(const int4*)(qw + base + 4);
        int w[8];
        w[0] = (int)rintf((float)(c0.x - zp) * factor);
        w[1] = (int)rintf((float)(c0.y - zp) * factor);
        w[2] = (int)rintf((float)(c0.z - zp) * factor);
        w[3] = (int)rintf((float)(c0.w - zp) * factor);
        w[4] = (int)rintf((float)(c1.x - zp) * factor);
        w[5] = (int)rintf((float)(c1.y - zp) * factor);
        w[6] = (int)rintf((float)(c1.z - zp) * factor);
        w[7] = (int)rintf((float)(c1.w - zp) * factor);
        uint2 pk;
        pk.x = (w[0] & 0xff) | ((w[1] & 0xff) << 8) | ((w[2] & 0xff) << 16) | ((w[3] & 0xff) << 24);
        pk.y = (w[4] & 0xff) | ((w[5] & 0xff) << 8) | ((w[6] & 0xff) << 16) | ((w[7] & 0xff) << 24);
        *(uint2*)(Bt8 + base) = pk;

        int s8 = w[0] + w[1] + w[2] + w[3] + w[4] + w[5] + w[6] + w[7];
#pragma unroll
        for (int off = 1; off < 16; off <<= 1) s8 += __shfl_xor(s8, off);
        if ((t & 15) == 0)
            Sw[n * NGROUP + g] = s8;     // coalesced, no atomic
    }
}

// ---------------------------------------------------------------------------
// Pipelined i8 GEMM with fragment register double-buffering.
// Epilogue: out[m][n] = xscale[m]*(fws[n]*iacc + czp[m]*WSf[n]) + bias[n]
// ---------------------------------------------------------------------------
__global__ __launch_bounds__(512, 1) void gemm_kernel(
        const char* __restrict__ A8,     // [M][K] int8
        const char* __restrict__ Bt8,    // [N][K] int8
        const float* __restrict__ xscale,
        const float* __restrict__ xzpc,
        const float* __restrict__ wsc,   // [N][32]
        const int* __restrict__ Sw,      // [N][32]
        const float* __restrict__ bias,  // [N]
        float* __restrict__ out)         // [M][N] f32
{
    __shared__ __align__(16) char As[4][ASLOT];   // 64 KiB
    __shared__ __align__(16) char Bs[4][BSLOT];   // 32 KiB
    __shared__ float fws_s[BN], wsf_s[BN];

    const int tid  = threadIdx.x;
    // XCD-aware decode: bid%8 is the XCD (round-robin dispatch); give each
    // XCD one bm row so its 32 blocks share a 1 MiB A-panel in private L2.
    const int bid  = blockIdx.x;
    const int bm   = bid & 7;
    const int bn   = bid >> 3;
    const int wave = tid >> 6;
    const int lane = tid & 63;
    const int wr   = wave >> 1;          // 0..3  -> 64-row band
    const int wcl  = wave & 1;           // 0..1  -> 64-col band
    const int lrow  = lane & 15;
    const int lquad = lane >> 4;         // 0..3 -> 16B k-chunk

    // --- per-column epilogue constants, before the pipeline starts ---
    if (tid < BN) {
        const int n = bn * BN + tid;
        const int4* s4 = (const int4*)(Sw + (size_t)n * NGROUP);
        int acc = 0;
#pragma unroll
        for (int p = 0; p < 8; ++p) { int4 v = s4[p]; acc += v.x + v.y + v.z + v.w; }
        const float4* w4 = (const float4*)(wsc + (size_t)n * NGROUP);
        float s = 0.f;
#pragma unroll
        for (int p = 0; p < 8; ++p) {
            float4 w = w4[p];
            s = fmaxf(s, fmaxf(fmaxf(w.x, w.y), fmaxf(w.z, w.w)));
        }
        const float fw = s * RQ_DOWN;
        fws_s[tid] = fw;
        wsf_s[tid] = fw * (float)acc;
    }
    // drain prologue vmem (clean vmcnt baseline for counted waits) + publish LDS
    asm volatile("s_waitcnt vmcnt(0) lgkmcnt(0)" ::: "memory");
    BARRIER();

    // --- staging addresses: gl2lds dst = uniform base + lane*16 (m104).
    const char* Ab = A8  + (size_t)(bm * BM) * K_DIM;
    const char* Bb = Bt8 + (size_t)(bn * BN) * K_DIM;
    const int lsub = lane >> 2;
    const int csrc = (lane & 3) ^ ((lane >> 3) & 3);
    const char* gA0 = Ab + (size_t)((wave      ) * 16 + lsub) * K_DIM + csrc * 16;
    const char* gA1 = Ab + (size_t)((wave + 8  ) * 16 + lsub) * K_DIM + csrc * 16;
    const char* gB0 = Bb + (size_t)((wave      ) * 16 + lsub) * K_DIM + csrc * 16;
    const int lA0 = wave * 1024;
    const int lA1 = 8192 + wave * 1024;
    const int lB0 = wave * 1024;

    // --- ds_read offsets (slot-relative), swizzle matches staging involution ---
    const int xq = (lquad ^ ((lrow >> 1) & 3)) * 16;
    int aoff[4], boff[4];
#pragma unroll
    for (int i = 0; i < 4; ++i)
        aoff[i] = (wr * 64 + i * 16 + lrow) * KSLICE + xq;
#pragma unroll
    for (int j = 0; j < 4; ++j)
        boff[j] = (wcl * 64 + j * 16 + lrow) * KSLICE + xq;

    int32x4_t iacc[4][4];
    const int32x4_t zi = {0, 0, 0, 0};
#pragma unroll
    for (int i = 0; i < 4; ++i)
#pragma unroll
        for (int j = 0; j < 4; ++j) iacc[i][j] = zi;

    int32x4_t afA[4], bfA[4], afB[4], bfB[4];

#define STAGE(t) {                                                   \
        const int sl_ = (t) & 3;                                     \
        const size_t k0_ = (size_t)(t) * KSLICE;                     \
        gl2lds16(gA0 + k0_, &As[sl_][0] + lA0);                      \
        gl2lds16(gA1 + k0_, &As[sl_][0] + lA1);                      \
        gl2lds16(gB0 + k0_, &Bs[sl_][0] + lB0);                      \
    }

#define READF(s, af, bf) {                                           \
        const char* Ap_ = &As[(s) & 3][0];                           \
        const char* Bp_ = &Bs[(s) & 3][0];                           \
        _Pragma("unroll")                                            \
        for (int i_ = 0; i_ < 4; ++i_)                               \
            af[i_] = *(const int32x4_t*)(Ap_ + aoff[i_]);            \
        _Pragma("unroll")                                            \
        for (int j_ = 0; j_ < 4; ++j_)                               \
            bf[j_] = *(const int32x4_t*)(Bp_ + boff[j_]);            \
    }

#define MFMAS(af, bf) {                                              \
        __builtin_amdgcn_s_setprio(1);                               \
        _Pragma("unroll")                                            \
        for (int i_ = 0; i_ < 4; ++i_)                               \
            _Pragma("unroll")                                        \
            for (int j_ = 0; j_ < 4; ++j_)                           \
                iacc[i_][j_] = __builtin_amdgcn_mfma_i32_16x16x64_i8(\
                    af[i_], bf[j_], iacc[i_][j_], 0, 0, 0);          \
        __builtin_amdgcn_s_setprio(0);                               \
    }

    // Body(s): STAGE(s+3) into freed slot; WAITVM(VMN) -> slice s+1 landed;
    // barrier publishes it; ds_read frags(s+1) into NXT regs; lgkmcnt(8)
    // guarantees only CUR's reads (issued last body) are complete —
    // sched_barrier stops MFMA hoisting (rule #18); MFMA(s) runs while NXT
    // reads + prefetch DMA are in flight; trailing barrier frees slot s&3.
#define BODY(s, VMN, CA, CB, NA, NB) {                               \
        if ((s) + 3 < NSLICE) STAGE((s) + 3);                        \
        WAITVM(VMN);                                                 \
        BARRIER();                                                   \
        READF((s) + 1, NA, NB);                                      \
        WAITLGKM(8);                                                 \
        __builtin_amdgcn_sched_barrier(0);                           \
        MFMAS(CA, CB);                                               \
        BARRIER();                                                   \
    }

    // ---- prologue: stage 0..2, land slice 0, read frags(0) ----
    STAGE(0); STAGE(1); STAGE(2);
    WAITVM(6);
    BARRIER();
    READF(0, afA, bfA);

    // ---- steady state: slices 0..59 in even/odd pairs ----
    for (int s = 0; s < NSLICE - 4; s += 2) {
        BODY(s,     6, afA, bfA, afB, bfB);
        BODY(s + 1, 6, afB, bfB, afA, bfA);
    }
    // ---- drain: slices 60..63 ----
    BODY(60, 6, afA, bfA, afB, bfB);     // stages 63; outstanding 61,62,63
    BODY(61, 3, afB, bfB, afA, bfA);     // no stage; wait slice 62
    // slice 62: wait slice 63, read frags(63), MFMA(62)
    WAITVM(0);
    BARRIER();
    READF(63, afB, bfB);
    WAITLGKM(8);
    __builtin_amdgcn_sched_barrier(0);
    MFMAS(afA, bfA);
    // slice 63: last MFMA, no barriers needed after
    WAITLGKM(0);
    __builtin_amdgcn_sched_barrier(0);
    MFMAS(afB, bfB);

    // --- epilogue: C/D layout col=lane&15, row=lquad*4+reg ---
    float fn[4], wf[4], bb[4];
    int ncol[4];
#pragma unroll
    for (int j = 0; j < 4; ++j) {
        const int ncl = wcl * 64 + j * 16 + lrow;
        ncol[j] = bn * BN + ncl;
        fn[j] = fws_s[ncl];
        wf[j] = wsf_s[ncl];
        bb[j] = bias[ncol[j]];
    }
    const int m0 = bm * BM + wr * 64;
#pragma unroll
    for (int i = 0; i < 4; ++i) {
#pragma unroll
        for (int r = 0; r < 4; ++r) {
            const int m = m0 + i * 16 + lquad * 4 + r;
            const float xs  = xscale[m];
            const float czp = xzpc[m];
            float* orow = out + (size_t)m * N_DIM;
#pragma unroll
            for (int j = 0; j < 4; ++j)
                orow[ncol[j]] = xs * (fn[j] * (float)iacc[i][j][r] + czp * wf[j]) + bb[j];
        }
    }
#undef BODY
#undef MFMAS
#undef READF
#undef STAGE
}

extern "C" void kernel_launch(void* const* d_in, const int* in_sizes, int n_in,
                              void* d_out, int out_size, void* d_ws, size_t ws_size,
                              hipStream_t stream) {
    const float* x     = (const float*)d_in[0];
    const int*   qw    = (const int*)d_in[1];
    const float* wsc   = (const float*)d_in[2];
    const int*   wzp   = (const int*)d_in[3];
    const float* bias  = (const float*)d_in[4];
    float* out = (float*)d_out;

    // workspace layout
    char* A8  = (char*)d_ws;                                   //  8 MiB
    char* Bt8 = A8 + (size_t)M_DIM * K_DIM;                    // 16 MiB
    float* xscale = (float*)(Bt8 + (size_t)N_DIM * K_DIM);     //  8 KiB
    float* xzpc   = xscale + M_DIM;                            //  8 KiB
    int*   Sw     = (int*)(xzpc + M_DIM);                      // 512 KiB

    prep_kernel<<<QUANT_BLOCKS + DEQ_BLOCKS, 256, 0, stream>>>(
        x, qw, wsc, wzp, A8, Bt8, xscale, xzpc, Sw);
    gemm_kernel<<<256, 512, 0, stream>>>(A8, Bt8, xscale, xzpc, wsc, Sw, bias, out);
}